// Round 6
// baseline (358.351 us; speedup 1.0000x reference)
//
#include <hip/hip_runtime.h>
#include <hip/hip_bf16.h>
#include <stdint.h>

// RoPE attention, B=2 S=2048 D=2048 H=16 hd=128.
// conv(all f32->bf16) -> Q/K(+rope)/V(->Vt) GEMMs (deep-pipelined, counted
// vmcnt, conflict-free swizzle) -> flash attention (round-5 structure)
// -> output GEMM (f32 out).

typedef __attribute__((ext_vector_type(4))) float f32x4;
typedef __attribute__((ext_vector_type(8))) short bf16x8;

typedef __attribute__((address_space(3))) unsigned int lds_u32;
typedef __attribute__((address_space(1))) const unsigned int gbl_u32;

__device__ __forceinline__ void async16(const void* g, void* l) {
  __builtin_amdgcn_global_load_lds((gbl_u32*)g, (lds_u32*)l, 16, 0, 0);
}

__device__ __forceinline__ float bf_to_f(unsigned short u) {
  union { unsigned int i; float f; } v; v.i = ((unsigned int)u) << 16; return v.f;
}
__device__ __forceinline__ unsigned short f_to_bf(float f) {
  union { float f; unsigned int i; } v; v.f = f;
  unsigned int r = v.i + 0x7FFFu + ((v.i >> 16) & 1u);  // RNE
  return (unsigned short)(r >> 16);
}
__device__ __forceinline__ unsigned int cvt_pk_bf16(float lo, float hi) {
  unsigned int r;
  asm("v_cvt_pk_bf16_f32 %0, %1, %2" : "=v"(r) : "v"(lo), "v"(hi));
  return r;
}

#define B_ 2
#define S_ 2048
#define D_ 2048
#define H_ 16
#define HD_ 128

// ---------------- fused f32 -> bf16 convert for x + 4 weights ----------------
__global__ __launch_bounds__(256) void conv_all(const float* __restrict__ x,
                                                const float* __restrict__ wq,
                                                const float* __restrict__ wk,
                                                const float* __restrict__ wv,
                                                const float* __restrict__ wo,
                                                unsigned short* __restrict__ xb,
                                                unsigned short* __restrict__ wb) {
  int i = blockIdx.x * 256 + threadIdx.x;  // [0, 6291456)
  const float* s;
  unsigned short* d;
  int off;
  if (i < 2097152) {
    s = x; d = xb; off = i;
  } else {
    int j = i - 2097152;
    int t = j >> 20;
    off = j & 1048575;
    s = (t == 0) ? wq : (t == 1) ? wk : (t == 2) ? wv : wo;
    d = wb + (size_t)t * 4194304;
  }
  float4 v = ((const float4*)s)[off];
  uint2 o;
  o.x = (unsigned int)f_to_bf(v.x) | ((unsigned int)f_to_bf(v.y) << 16);
  o.y = (unsigned int)f_to_bf(v.z) | ((unsigned int)f_to_bf(v.w) << 16);
  ((uint2*)d)[off] = o;
}

// ---------------- rope cos/sin table: [S][64] ----------------
__global__ __launch_bounds__(256) void rope_table_kernel(float* __restrict__ cosT,
                                                         float* __restrict__ sinT) {
  int i = blockIdx.x * 256 + threadIdx.x;  // S*64 entries
  int s = i >> 6, j = i & 63;
  float inv = powf(10000.0f, -(float)(2 * j) * (1.0f / 128.0f));
  float ang = (float)s * inv;
  float sv, cv;
  sincosf(ang, &sv, &cv);
  cosT[i] = cv;
  sinT[i] = sv;
}

// ---------------- deep-pipelined GEMM: C[4096,2048] = A[4096,2048] * B[2048,2048]^T
// BM=128 BN=256 BK=32, 8 waves (2Mx4N, per-wave 64x64), grid 256 (1 block/CU).
// 4-deep LDS pipeline, prefetch 3 K-tiles ahead, gate = vmcnt(6)+s_barrier
// (never drains to 0 in steady state). LDS rows are 64B: swizzle
// byte ^= ((row>>1)&3)<<4 makes ds_read_b128 conflict-free; global source
// pre-swizzled so global_load_lds dest stays linear.
// MODE 0: bf16 out. MODE 1: f32 out. MODE 2: bf16 + RoPE (K proj).
// MODE 3: bf16 transposed into Vt[b*2048 + n][s] (V proj).
#define GK 2048
#define GNT 64  // GK/32
template <int MODE>
__global__ __launch_bounds__(512, 1) void gemm8p(const unsigned short* __restrict__ A,
                                                 const unsigned short* __restrict__ Bm,
                                                 unsigned short* __restrict__ Cb,
                                                 float* __restrict__ Cf,
                                                 const float* __restrict__ cosT,
                                                 const float* __restrict__ sinT) {
  __shared__ unsigned short sA[4][128 * 32];  // 4 x 8 KB
  __shared__ unsigned short sB[4][256 * 32];  // 4 x 16 KB
  const int tid = threadIdx.x;
  const int l = tid & 63, w = tid >> 6;
  const int lane15 = l & 15, lhi = l >> 4;
  const int wm = w >> 2, wn = w & 3;
  // XCD-bijective block swizzle: XCD x owns bn = x (1 MB B-panel -> its L2)
  const int wgn = (blockIdx.x & 7) * 32 + (blockIdx.x >> 3);
  const int bm = wgn & 31;   // 32 M-tiles of 128
  const int bn = wgn >> 5;   // 8  N-tiles of 256

  // staging assignment: per thread 3 x 16B per K-tile (1 A + 2 B)
  const int srow = tid >> 2;                       // 0..127
  const int colD = (tid & 3) << 4;                 // dest byte col in 64B row
  const int colS = colD ^ (((srow >> 1) & 3) << 4);  // pre-swizzled source col
  const unsigned short* aSrc  = A  + ((size_t)(bm * 128 + srow)) * GK + (colS >> 1);
  const unsigned short* bSrc0 = Bm + ((size_t)(bn * 256 + srow)) * GK + (colS >> 1);
  const unsigned short* bSrc1 = Bm + ((size_t)(bn * 256 + 128 + srow)) * GK + (colS >> 1);
  const unsigned int aOff  = srow * 64 + colD;
  const unsigned int bOff0 = srow * 64 + colD;
  const unsigned int bOff1 = (128 + srow) * 64 + colD;

#define STAGE(q)                                                   \
  do {                                                             \
    async16(aSrc,  (char*)sA + (q) * 8192  + aOff);  aSrc  += 32;  \
    async16(bSrc0, (char*)sB + (q) * 16384 + bOff0); bSrc0 += 32;  \
    async16(bSrc1, (char*)sB + (q) * 16384 + bOff1); bSrc1 += 32;  \
  } while (0)

  f32x4 acc[4][4];
  const f32x4 zero = {0.f, 0.f, 0.f, 0.f};
#pragma unroll
  for (int i = 0; i < 4; i++)
#pragma unroll
    for (int j = 0; j < 4; j++) acc[i][j] = zero;

  // per-thread read geometry: slot XOR spreads the 4 16B slots of a 64B row
  const int g = (lhi * 16) ^ (((lane15 >> 1) & 3) << 4);  // byte col
  const unsigned int aRd = (wm * 64 + lane15) * 64 + g;   // + mi*1024
  const unsigned int bRd = (wn * 64 + lane15) * 64 + g;   // + ni*1024

  // prologue: stage tiles 0,1,2 then gate tile 0
  STAGE(0);
  STAGE(1);
  STAGE(2);
  asm volatile("s_waitcnt vmcnt(6)" ::: "memory");
  __builtin_amdgcn_s_barrier();
  asm volatile("" ::: "memory");
  __builtin_amdgcn_sched_barrier(0);

#pragma unroll 4
  for (int t = 0; t < GNT; ++t) {
    if (t < GNT - 3) STAGE((t + 3) & 3);

    bf16x8 af[4], bfr[4];
    const char* aBase = (const char*)sA + (t & 3) * 8192 + aRd;
    const char* bBase = (const char*)sB + (t & 3) * 16384 + bRd;
#pragma unroll
    for (int mi = 0; mi < 4; mi++) af[mi] = *(const bf16x8*)(aBase + mi * 1024);
#pragma unroll
    for (int ni = 0; ni < 4; ni++) bfr[ni] = *(const bf16x8*)(bBase + ni * 1024);

    __builtin_amdgcn_s_setprio(1);
#pragma unroll
    for (int mi = 0; mi < 4; mi++)
#pragma unroll
      for (int ni = 0; ni < 4; ni++)
        acc[mi][ni] = __builtin_amdgcn_mfma_f32_16x16x32_bf16(af[mi], bfr[ni], acc[mi][ni], 0, 0, 0);
    __builtin_amdgcn_s_setprio(0);

    // gate for tile t+1 (its loads are the oldest still possibly in flight)
    if (t <= GNT - 4) {
      asm volatile("s_waitcnt vmcnt(6)" ::: "memory");
    } else if (t == GNT - 3) {
      asm volatile("s_waitcnt vmcnt(3)" ::: "memory");
    } else {
      asm volatile("s_waitcnt vmcnt(0)" ::: "memory");
    }
    __builtin_amdgcn_s_barrier();
    asm volatile("" ::: "memory");
    __builtin_amdgcn_sched_barrier(0);
  }
#undef STAGE

  // epilogue: C/D layout col=lane&15, row=(lane>>4)*4+r
  const int N = 2048;
#pragma unroll
  for (int mi = 0; mi < 4; mi++) {
    int m0 = bm * 128 + wm * 64 + mi * 16 + lhi * 4;
#pragma unroll
    for (int ni = 0; ni < 4; ni++) {
      int n = bn * 256 + wn * 64 + ni * 16 + lane15;
      if constexpr (MODE == 0) {
#pragma unroll
        for (int r = 0; r < 4; r++) Cb[(size_t)(m0 + r) * N + n] = f_to_bf(acc[mi][ni][r]);
      } else if constexpr (MODE == 1) {
#pragma unroll
        for (int r = 0; r < 4; r++) Cf[(size_t)(m0 + r) * N + n] = acc[mi][ni][r];
      } else if constexpr (MODE == 2) {
        int s0 = m0 & (S_ - 1);
        int jp = (n & (HD_ - 1)) >> 1;
        int odd = n & 1;
#pragma unroll
        for (int r = 0; r < 4; r++) {
          float own = acc[mi][ni][r];
          float prt = __shfl_xor(own, 1);
          float c = cosT[(s0 + r) * 64 + jp];
          float sn = sinT[(s0 + r) * 64 + jp];
          float outv = odd ? fmaf(prt, sn, own * c) : own * c - prt * sn;
          Cb[(size_t)(m0 + r) * N + n] = f_to_bf(outv);
        }
      } else {  // MODE 3: Vt[b*2048 + n][s], 4 consecutive s packed
        int s0 = m0 & (S_ - 1);
        size_t row = (size_t)((m0 >> 11) * D_ + n);
        uint2 st;
        st.x = (unsigned int)f_to_bf(acc[mi][ni][0]) | ((unsigned int)f_to_bf(acc[mi][ni][1]) << 16);
        st.y = (unsigned int)f_to_bf(acc[mi][ni][2]) | ((unsigned int)f_to_bf(acc[mi][ni][3]) << 16);
        *(uint2*)(Cb + row * S_ + s0) = st;
      }
    }
  }
}

// ---------------- flash attention (round-5 structure, unchanged) ----------------
// grid (8, 32): 256 blocks of 512 threads = 1 block/CU.
// XCD swizzle: blockIdx.x owns bh in [bx*4, bx*4+4) (4 MB KV = its L2).
// 8 waves x QBLK=32 (2 stripes of 16); waves 0-3 stage K, 4-7 stage V.
__global__ __launch_bounds__(512, 2) void attn_kernel(const unsigned short* __restrict__ Q,
                                                      const unsigned short* __restrict__ K,
                                                      const unsigned short* __restrict__ Vt,
                                                      unsigned short* __restrict__ ctx,
                                                      const float* __restrict__ cosT,
                                                      const float* __restrict__ sinT) {
  __shared__ unsigned short sK[2][64 * 128];
  __shared__ unsigned short sV[2][128 * 64];
  __shared__ unsigned short sP[8][32 * 72];
  const int tid = threadIdx.x, l = tid & 63, w = tid >> 6;
  const int lane15 = l & 15, lhi = l >> 4;
  const int bh = blockIdx.x * 4 + (blockIdx.y >> 3);
  const int qt = blockIdx.y & 7;
  const int b = bh >> 4, h = bh & 15;
  const int q0 = qt * 256;
  const unsigned short* Kg = K + ((size_t)(b * S_)) * D_ + h * HD_;
  const unsigned short* Vg = Vt + ((size_t)bh * HD_) * S_;
  const float scale = 0.08838834764831845f;  // 1/sqrt(128)

  const unsigned short* gp0;
  const unsigned short* gp1;
  const unsigned short* gp2;
  const unsigned short* gp3;
  unsigned int ldsOff[4];
  int gstride;
  if (w < 4) {
    const unsigned short* t0;
#pragma unroll
    for (int i = 0; i < 4; i++) {
      int row = w * 16 + i * 4 + (l >> 4);
      int colD = (l & 15) << 4;
      int colS = colD ^ ((row & 7) << 4);
      t0 = Kg + (size_t)row * D_ + (colS >> 1);
      if (i == 0) gp0 = t0; else if (i == 1) gp1 = t0; else if (i == 2) gp2 = t0; else gp3 = t0;
      ldsOff[i] = row * 256 + colD;
    }
    gstride = 64 * D_;
  } else {
    const unsigned short* t0;
#pragma unroll
    for (int i = 0; i < 4; i++) {
      int row = (w - 4) * 32 + i * 8 + (l >> 3);
      int colD = (l & 7) << 4;
      int colS = colD ^ ((row & 7) << 4);
      t0 = Vg + (size_t)row * S_ + (colS >> 1);
      if (i == 0) gp0 = t0; else if (i == 1) gp1 = t0; else if (i == 2) gp2 = t0; else gp3 = t0;
      ldsOff[i] = row * 128 + colD;
    }
    gstride = 64;
  }

  bf16x8 qf[2][4];
#pragma unroll
  for (int s = 0; s < 2; s++) {
    int s_q = q0 + w * 32 + s * 16 + lane15;
    const unsigned short* Qrow = Q + ((size_t)(b * S_ + s_q)) * D_ + h * HD_;
#pragma unroll
    for (int kc = 0; kc < 4; kc++) {
      int d0 = kc * 32 + lhi * 8;
      uint4 raw = *(const uint4*)(Qrow + d0);
      float4 cv = *(const float4*)(cosT + (size_t)s_q * 64 + (d0 >> 1));
      float4 sv = *(const float4*)(sinT + (size_t)s_q * 64 + (d0 >> 1));
      unsigned int u[4] = {raw.x, raw.y, raw.z, raw.w};
      float cc[4] = {cv.x, cv.y, cv.z, cv.w};
      float ss[4] = {sv.x, sv.y, sv.z, sv.w};
      unsigned int o[4];
#pragma unroll
      for (int p = 0; p < 4; p++) {
        float re = bf_to_f((unsigned short)(u[p] & 0xffffu));
        float im = bf_to_f((unsigned short)(u[p] >> 16));
        float orr = (re * cc[p] - im * ss[p]) * scale;
        float oi = (re * ss[p] + im * cc[p]) * scale;
        o[p] = (unsigned int)f_to_bf(orr) | ((unsigned int)f_to_bf(oi) << 16);
      }
      union { uint4 u4; bf16x8 v; } cvt;
      cvt.u4.x = o[0]; cvt.u4.y = o[1]; cvt.u4.z = o[2]; cvt.u4.w = o[3];
      qf[s][kc] = cvt.v;
    }
  }

  float mrun[2] = {-1e30f, -1e30f}, lrun[2] = {0.f, 0.f};
  const f32x4 zero = {0.f, 0.f, 0.f, 0.f};
  f32x4 oacc[2][8];
#pragma unroll
  for (int s = 0; s < 2; s++)
#pragma unroll
    for (int nf = 0; nf < 8; nf++) oacc[s][nf] = zero;

  {
    char* base = (w < 4) ? (char*)&sK[0][0] : (char*)&sV[0][0];
    async16(gp0, base + ldsOff[0]);
    async16(gp1, base + ldsOff[1]);
    async16(gp2, base + ldsOff[2]);
    async16(gp3, base + ldsOff[3]);
    gp0 += gstride; gp1 += gstride; gp2 += gstride; gp3 += gstride;
  }

  for (int t = 0; t < 32; ++t) {
    const int cur = t & 1;
    __syncthreads();
    if (t < 31) {
      char* base = (w < 4) ? (char*)&sK[cur ^ 1][0] : (char*)&sV[cur ^ 1][0];
      async16(gp0, base + ldsOff[0]);
      async16(gp1, base + ldsOff[1]);
      async16(gp2, base + ldsOff[2]);
      async16(gp3, base + ldsOff[3]);
      gp0 += gstride; gp1 += gstride; gp2 += gstride; gp3 += gstride;
    }
    const unsigned short* sKc = sK[cur];
    const unsigned short* sVc = sV[cur];

    f32x4 sacc[2][4];
#pragma unroll
    for (int s = 0; s < 2; s++)
#pragma unroll
      for (int n = 0; n < 4; n++) sacc[s][n] = zero;
    __builtin_amdgcn_s_setprio(1);
#pragma unroll
    for (int n = 0; n < 4; n++) {
      int row = n * 16 + lane15;
#pragma unroll
      for (int kc = 0; kc < 4; kc++) {
        bf16x8 kf = *(const bf16x8*)((const char*)sKc + row * 256 +
                                     ((kc * 64 + lhi * 16) ^ ((row & 7) << 4)));
        sacc[0][n] = __builtin_amdgcn_mfma_f32_16x16x32_bf16(kf, qf[0][kc], sacc[0][n], 0, 0, 0);
        sacc[1][n] = __builtin_amdgcn_mfma_f32_16x16x32_bf16(kf, qf[1][kc], sacc[1][n], 0, 0, 0);
      }
    }
    __builtin_amdgcn_s_setprio(0);

#pragma unroll
    for (int s = 0; s < 2; s++) {
      float m0 = fmaxf(fmaxf(sacc[s][0][0], sacc[s][0][1]), fmaxf(sacc[s][0][2], sacc[s][0][3]));
      float m1 = fmaxf(fmaxf(sacc[s][1][0], sacc[s][1][1]), fmaxf(sacc[s][1][2], sacc[s][1][3]));
      float m2 = fmaxf(fmaxf(sacc[s][2][0], sacc[s][2][1]), fmaxf(sacc[s][2][2], sacc[s][2][3]));
      float m3 = fmaxf(fmaxf(sacc[s][3][0], sacc[s][3][1]), fmaxf(sacc[s][3][2], sacc[s][3][3]));
      float pmax = fmaxf(fmaxf(m0, m1), fmaxf(m2, m3));
      pmax = fmaxf(pmax, __shfl_xor(pmax, 16));
      pmax = fmaxf(pmax, __shfl_xor(pmax, 32));
      if (!__all(pmax - mrun[s] <= 8.0f)) {
        float mnew = fmaxf(mrun[s], pmax);
        float alpha = __expf(mrun[s] - mnew);
        lrun[s] *= alpha;
        float af[4];
#pragma unroll
        for (int r = 0; r < 4; r++) af[r] = __shfl(alpha, lhi * 4 + r);
#pragma unroll
        for (int nf = 0; nf < 8; nf++)
#pragma unroll
          for (int r = 0; r < 4; r++) oacc[s][nf][r] *= af[r];
        mrun[s] = mnew;
      }
      const float l2e = 1.44269504f;
      float mb = mrun[s] * l2e;
      float rs = 0.f;
      float p[4][4];
#pragma unroll
      for (int n = 0; n < 4; n++)
#pragma unroll
        for (int r = 0; r < 4; r++) {
          float pv = exp2f(sacc[s][n][r] * l2e - mb);
          p[n][r] = pv;
          rs += pv;
        }
      rs += __shfl_xor(rs, 16);
      rs += __shfl_xor(rs, 32);
      lrun[s] += rs;
#pragma unroll
      for (int n = 0; n < 4; n++) {
        uint2 st;
        st.x = cvt_pk_bf16(p[n][0], p[n][1]);
        st.y = cvt_pk_bf16(p[n][2], p[n][3]);
        *(uint2*)&sP[w][(s * 16 + lane15) * 72 + n * 16 + lhi * 4] = st;
      }
    }
    asm volatile("s_waitcnt lgkmcnt(0)" ::: "memory");
    __builtin_amdgcn_sched_barrier(0);
    bf16x8 pf[2][2];
#pragma unroll
    for (int s = 0; s < 2; s++)
#pragma unroll
      for (int kc = 0; kc < 2; kc++)
        pf[s][kc] = *(const bf16x8*)&sP[w][(s * 16 + lane15) * 72 + kc * 32 + lhi * 8];

    __builtin_amdgcn_s_setprio(1);
#pragma unroll
    for (int nf = 0; nf < 8; nf++) {
      int row = nf * 16 + lane15;
#pragma unroll
      for (int kc = 0; kc < 2; kc++) {
        bf16x8 vf = *(const bf16x8*)((const char*)sVc + row * 128 +
                                     ((kc * 64 + lhi * 16) ^ ((row & 7) << 4)));
        oacc[0][nf] = __builtin_amdgcn_mfma_f32_16x16x32_bf16(pf[0][kc], vf, oacc[0][nf], 0, 0, 0);
        oacc[1][nf] = __builtin_amdgcn_mfma_f32_16x16x32_bf16(pf[1][kc], vf, oacc[1][nf], 0, 0, 0);
      }
    }
    __builtin_amdgcn_s_setprio(0);
  }

#pragma unroll
  for (int s = 0; s < 2; s++) {
    float inv = 1.0f / lrun[s];
    float invr[4];
#pragma unroll
    for (int r = 0; r < 4; r++) invr[r] = __shfl(inv, lhi * 4 + r);
    unsigned short* Og = ctx + ((size_t)(b * S_ + q0 + w * 32 + s * 16)) * D_ + h * HD_;
#pragma unroll
    for (int r = 0; r < 4; r++) {
      int qrow = lhi * 4 + r;
#pragma unroll
      for (int nf = 0; nf < 8; nf++)
        Og[(size_t)qrow * D_ + nf * 16 + lane15] = f_to_bf(oacc[s][nf][r] * invr[r]);
    }
  }
}

// ---------------- launcher ----------------
extern "C" void kernel_launch(void* const* d_in, const int* in_sizes, int n_in,
                              void* d_out, int out_size, void* d_ws, size_t ws_size,
                              hipStream_t stream) {
  (void)in_sizes; (void)n_in; (void)out_size; (void)ws_size;
  const float* x = (const float*)d_in[0];
  const float* wq = (const float*)d_in[1];
  const float* wk = (const float*)d_in[2];
  const float* wv = (const float*)d_in[3];
  const float* wo = (const float*)d_in[4];
  float* out = (float*)d_out;

  char* ws = (char*)d_ws;
  const size_t MB = 1024 * 1024;
  unsigned short* xb  = (unsigned short*)(ws + 0 * MB);    // 16 MB; later aliased as ctx
  unsigned short* wqb = (unsigned short*)(ws + 16 * MB);   // 8 MB (wq..wo contiguous)
  unsigned short* wkb = (unsigned short*)(ws + 24 * MB);
  unsigned short* wvb = (unsigned short*)(ws + 32 * MB);
  unsigned short* wob = (unsigned short*)(ws + 40 * MB);
  unsigned short* Qb  = (unsigned short*)(ws + 48 * MB);   // 16 MB
  unsigned short* Kb  = (unsigned short*)(ws + 64 * MB);   // 16 MB
  unsigned short* Vtb = (unsigned short*)(ws + 80 * MB);   // 16 MB
  float* cosT = (float*)(ws + 96 * MB);                    // 0.5 MB
  float* sinT = (float*)(ws + 96 * MB + 524288);           // 0.5 MB
  unsigned short* ctxb = xb;  // x_bf16 dead after QKV GEMMs

  conv_all<<<24576, 256, 0, stream>>>(x, wq, wk, wv, wo, xb, wqb);
  rope_table_kernel<<<512, 256, 0, stream>>>(cosT, sinT);

  gemm8p<0><<<256, 512, 0, stream>>>(xb, wqb, Qb, nullptr, nullptr, nullptr);
  gemm8p<2><<<256, 512, 0, stream>>>(xb, wkb, Kb, nullptr, cosT, sinT);
  gemm8p<3><<<256, 512, 0, stream>>>(xb, wvb, Vtb, nullptr, nullptr, nullptr);

  attn_kernel<<<dim3(8, 32), 512, 0, stream>>>(Qb, Kb, Vtb, ctxb, cosT, sinT);

  gemm8p<1><<<256, 512, 0, stream>>>(ctxb, wob, nullptr, out, nullptr, nullptr);
}

// Round 7
// 314.616 us; speedup vs baseline: 1.1390x; 1.1390x over previous
//
#include <hip/hip_runtime.h>
#include <hip/hip_bf16.h>
#include <stdint.h>

// RoPE attention, B=2 S=2048 D=2048 H=16 hd=128.
// conv(all f32->bf16) -> Q GEMM | K GEMM(+rope) | V GEMM(->Vt)
//   -> flash attention (8-wave, double-buffered async staging, QBLK=32/wave
//      shared fragments, XCD swizzle, swapped-QK^T in-register softmax in
//      log2-units, merged defer-max branch, cvt_pk) -> output GEMM (f32).

typedef __attribute__((ext_vector_type(4))) float f32x4;
typedef __attribute__((ext_vector_type(8))) short bf16x8;

typedef __attribute__((address_space(3))) unsigned int lds_u32;
typedef __attribute__((address_space(1))) const unsigned int gbl_u32;

__device__ __forceinline__ void async16(const void* g, void* l) {
  __builtin_amdgcn_global_load_lds((gbl_u32*)g, (lds_u32*)l, 16, 0, 0);
}

__device__ __forceinline__ float bf_to_f(unsigned short u) {
  union { unsigned int i; float f; } v; v.i = ((unsigned int)u) << 16; return v.f;
}
__device__ __forceinline__ unsigned short f_to_bf(float f) {
  union { float f; unsigned int i; } v; v.f = f;
  unsigned int r = v.i + 0x7FFFu + ((v.i >> 16) & 1u);  // RNE
  return (unsigned short)(r >> 16);
}
__device__ __forceinline__ unsigned int cvt_pk_bf16(float lo, float hi) {
  unsigned int r;
  asm("v_cvt_pk_bf16_f32 %0, %1, %2" : "=v"(r) : "v"(lo), "v"(hi));
  return r;
}

#define B_ 2
#define S_ 2048
#define D_ 2048
#define H_ 16
#define HD_ 128

// ---------------- fused f32 -> bf16 convert for x + 4 weights ----------------
__global__ __launch_bounds__(256) void conv_all(const float* __restrict__ x,
                                                const float* __restrict__ wq,
                                                const float* __restrict__ wk,
                                                const float* __restrict__ wv,
                                                const float* __restrict__ wo,
                                                unsigned short* __restrict__ xb,
                                                unsigned short* __restrict__ wb) {
  int i = blockIdx.x * 256 + threadIdx.x;  // [0, 6291456)
  const float* s;
  unsigned short* d;
  int off;
  if (i < 2097152) {
    s = x; d = xb; off = i;
  } else {
    int j = i - 2097152;
    int t = j >> 20;
    off = j & 1048575;
    s = (t == 0) ? wq : (t == 1) ? wk : (t == 2) ? wv : wo;
    d = wb + (size_t)t * 4194304;
  }
  float4 v = ((const float4*)s)[off];
  uint2 o;
  o.x = (unsigned int)f_to_bf(v.x) | ((unsigned int)f_to_bf(v.y) << 16);
  o.y = (unsigned int)f_to_bf(v.z) | ((unsigned int)f_to_bf(v.w) << 16);
  ((uint2*)d)[off] = o;
}

// ---------------- rope cos/sin table: [S][64] ----------------
__global__ __launch_bounds__(256) void rope_table_kernel(float* __restrict__ cosT,
                                                         float* __restrict__ sinT) {
  int i = blockIdx.x * 256 + threadIdx.x;  // S*64 entries
  int s = i >> 6, j = i & 63;
  float inv = powf(10000.0f, -(float)(2 * j) * (1.0f / 128.0f));
  float ang = (float)s * inv;
  float sv, cv;
  sincosf(ang, &sv, &cv);
  cosT[i] = cv;
  sinT[i] = sv;
}

// ---------------- GEMM: C[M,N] = A[M,K] * Bmat[N,K]^T -----------------------
// m97 structure: 128x128 tile, BK=32, 4 waves, global_load_lds w=16.
// launch_bounds(256,3): cap VGPR for 3 waves/SIMD (12 waves/CU, m97-class).
// MODE 0: bf16 out. MODE 1: f32 out. MODE 2: bf16 + RoPE (K proj).
// MODE 3: bf16 transposed into Vt[b*2048 + n][s] (V proj).
template <int MODE>
__global__ __launch_bounds__(256, 3) void gemm_bt(const unsigned short* __restrict__ A,
                                                  const unsigned short* __restrict__ Bm,
                                                  unsigned short* __restrict__ Cb,
                                                  float* __restrict__ Cf,
                                                  const float* __restrict__ cosT,
                                                  const float* __restrict__ sinT,
                                                  int M, int N, int K) {
  __shared__ unsigned short sA[128 * 32];
  __shared__ unsigned short sB[128 * 32];
  const int tid = threadIdx.x;
  const int l = tid & 63, wv = tid >> 6;
  const int lane15 = l & 15, lhi = l >> 4;
  const int wm = wv >> 1, wn = wv & 1;
  const int bm = blockIdx.x, bn = blockIdx.y;
  const unsigned short* Ag = A + (size_t)bm * 128 * K;
  const unsigned short* Bg = Bm + (size_t)bn * 128 * K;

  f32x4 acc[4][4];
  const f32x4 zero = {0.f, 0.f, 0.f, 0.f};
#pragma unroll
  for (int i = 0; i < 4; i++)
#pragma unroll
    for (int j = 0; j < 4; j++) acc[i][j] = zero;

  for (int k0 = 0; k0 < K; k0 += 32) {
    __syncthreads();
#pragma unroll
    for (int i = 0; i < 2; i++) {
      int c = i * 256 + tid;
      int row = c >> 2, col = (c & 3) << 3;
      async16(Ag + (size_t)row * K + k0 + col, &sA[c * 8]);
      async16(Bg + (size_t)row * K + k0 + col, &sB[c * 8]);
    }
    __syncthreads();

    bf16x8 af[4], bfr[4];
#pragma unroll
    for (int i = 0; i < 4; i++)
      af[i] = *(const bf16x8*)&sA[(wm * 64 + i * 16 + lane15) * 32 + lhi * 8];
#pragma unroll
    for (int j = 0; j < 4; j++)
      bfr[j] = *(const bf16x8*)&sB[(wn * 64 + j * 16 + lane15) * 32 + lhi * 8];
#pragma unroll
    for (int i = 0; i < 4; i++)
#pragma unroll
      for (int j = 0; j < 4; j++)
        acc[i][j] = __builtin_amdgcn_mfma_f32_16x16x32_bf16(af[i], bfr[j], acc[i][j], 0, 0, 0);
  }

  // epilogue: C/D layout col=lane&15, row=(lane>>4)*4+r
#pragma unroll
  for (int i = 0; i < 4; i++) {
    int m0 = bm * 128 + wm * 64 + i * 16 + lhi * 4;
#pragma unroll
    for (int j = 0; j < 4; j++) {
      int n = bn * 128 + wn * 64 + j * 16 + lane15;
      if constexpr (MODE == 0) {
#pragma unroll
        for (int r = 0; r < 4; r++) Cb[(size_t)(m0 + r) * N + n] = f_to_bf(acc[i][j][r]);
      } else if constexpr (MODE == 1) {
#pragma unroll
        for (int r = 0; r < 4; r++) Cf[(size_t)(m0 + r) * N + n] = acc[i][j][r];
      } else if constexpr (MODE == 2) {
        int s0 = m0 & (S_ - 1);
        int jp = (n & (HD_ - 1)) >> 1;
        int odd = n & 1;
#pragma unroll
        for (int r = 0; r < 4; r++) {
          float own = acc[i][j][r];
          float prt = __shfl_xor(own, 1);
          float c = cosT[(s0 + r) * 64 + jp];
          float sn = sinT[(s0 + r) * 64 + jp];
          float outv = odd ? fmaf(prt, sn, own * c) : own * c - prt * sn;
          Cb[(size_t)(m0 + r) * N + n] = f_to_bf(outv);
        }
      } else {  // MODE 3: Vt[b*2048 + n][s], 4 consecutive s packed
        int s0 = m0 & (S_ - 1);
        size_t row = (size_t)((m0 >> 11) * D_ + n);
        uint2 st;
        st.x = (unsigned int)f_to_bf(acc[i][j][0]) | ((unsigned int)f_to_bf(acc[i][j][1]) << 16);
        st.y = (unsigned int)f_to_bf(acc[i][j][2]) | ((unsigned int)f_to_bf(acc[i][j][3]) << 16);
        *(uint2*)(Cb + row * S_ + s0) = st;
      }
    }
  }
}

// ---------------- flash attention ----------------
// grid (8, 32): 256 blocks of 512 threads = 1 block/CU.
// XCD swizzle: blockIdx.x owns bh in [bx*4, bx*4+4) (4 MB KV = its L2).
// 8 waves x QBLK=32 (2 stripes of 16); waves 0-3 stage K, 4-7 stage V.
// Scores kept in log2-units (scale*log2e folded into Q fragments).
__global__ __launch_bounds__(512, 2) void attn_kernel(const unsigned short* __restrict__ Q,
                                                      const unsigned short* __restrict__ K,
                                                      const unsigned short* __restrict__ Vt,
                                                      unsigned short* __restrict__ ctx,
                                                      const float* __restrict__ cosT,
                                                      const float* __restrict__ sinT) {
  __shared__ unsigned short sK[2][64 * 128];
  __shared__ unsigned short sV[2][128 * 64];
  __shared__ unsigned short sP[8][32 * 72];
  const int tid = threadIdx.x, l = tid & 63, w = tid >> 6;
  const int lane15 = l & 15, lhi = l >> 4;
  const int bh = blockIdx.x * 4 + (blockIdx.y >> 3);
  const int qt = blockIdx.y & 7;
  const int b = bh >> 4, h = bh & 15;
  const int q0 = qt * 256;
  const unsigned short* Kg = K + ((size_t)(b * S_)) * D_ + h * HD_;
  const unsigned short* Vg = Vt + ((size_t)bh * HD_) * S_;
  const float qscale = 0.08838834764831845f * 1.44269504f;  // scale * log2(e)
  const float THR = 11.5415603f;                            // 8 * log2(e)

  const unsigned short* gp0;
  const unsigned short* gp1;
  const unsigned short* gp2;
  const unsigned short* gp3;
  unsigned int ldsOff[4];
  int gstride;
  if (w < 4) {
    const unsigned short* t0;
#pragma unroll
    for (int i = 0; i < 4; i++) {
      int row = w * 16 + i * 4 + (l >> 4);
      int colD = (l & 15) << 4;
      int colS = colD ^ ((row & 7) << 4);
      t0 = Kg + (size_t)row * D_ + (colS >> 1);
      if (i == 0) gp0 = t0; else if (i == 1) gp1 = t0; else if (i == 2) gp2 = t0; else gp3 = t0;
      ldsOff[i] = row * 256 + colD;
    }
    gstride = 64 * D_;
  } else {
    const unsigned short* t0;
#pragma unroll
    for (int i = 0; i < 4; i++) {
      int row = (w - 4) * 32 + i * 8 + (l >> 3);
      int colD = (l & 7) << 4;
      int colS = colD ^ ((row & 7) << 4);
      t0 = Vg + (size_t)row * S_ + (colS >> 1);
      if (i == 0) gp0 = t0; else if (i == 1) gp1 = t0; else if (i == 2) gp2 = t0; else gp3 = t0;
      ldsOff[i] = row * 128 + colD;
    }
    gstride = 64;
  }

  // Q load + RoPE + qscale (once per block; pairs in-lane)
  bf16x8 qf[2][4];
#pragma unroll
  for (int s = 0; s < 2; s++) {
    int s_q = q0 + w * 32 + s * 16 + lane15;
    const unsigned short* Qrow = Q + ((size_t)(b * S_ + s_q)) * D_ + h * HD_;
#pragma unroll
    for (int kc = 0; kc < 4; kc++) {
      int d0 = kc * 32 + lhi * 8;
      uint4 raw = *(const uint4*)(Qrow + d0);
      float4 cv = *(const float4*)(cosT + (size_t)s_q * 64 + (d0 >> 1));
      float4 sv = *(const float4*)(sinT + (size_t)s_q * 64 + (d0 >> 1));
      unsigned int u[4] = {raw.x, raw.y, raw.z, raw.w};
      float cc[4] = {cv.x, cv.y, cv.z, cv.w};
      float ss[4] = {sv.x, sv.y, sv.z, sv.w};
      unsigned int o[4];
#pragma unroll
      for (int p = 0; p < 4; p++) {
        float re = bf_to_f((unsigned short)(u[p] & 0xffffu));
        float im = bf_to_f((unsigned short)(u[p] >> 16));
        float orr = (re * cc[p] - im * ss[p]) * qscale;
        float oi = (re * ss[p] + im * cc[p]) * qscale;
        o[p] = (unsigned int)f_to_bf(orr) | ((unsigned int)f_to_bf(oi) << 16);
      }
      union { uint4 u4; bf16x8 v; } cvt;
      cvt.u4.x = o[0]; cvt.u4.y = o[1]; cvt.u4.z = o[2]; cvt.u4.w = o[3];
      qf[s][kc] = cvt.v;
    }
  }

  float mrun[2] = {-1e30f, -1e30f}, lrun[2] = {0.f, 0.f};
  const f32x4 zero = {0.f, 0.f, 0.f, 0.f};
  f32x4 oacc[2][8];
#pragma unroll
  for (int s = 0; s < 2; s++)
#pragma unroll
    for (int nf = 0; nf < 8; nf++) oacc[s][nf] = zero;

  {
    char* base = (w < 4) ? (char*)&sK[0][0] : (char*)&sV[0][0];
    async16(gp0, base + ldsOff[0]);
    async16(gp1, base + ldsOff[1]);
    async16(gp2, base + ldsOff[2]);
    async16(gp3, base + ldsOff[3]);
    gp0 += gstride; gp1 += gstride; gp2 += gstride; gp3 += gstride;
  }

  for (int t = 0; t < 32; ++t) {
    const int cur = t & 1;
    __syncthreads();  // drains prev-iteration loads (had full compute to land)
    if (t < 31) {
      char* base = (w < 4) ? (char*)&sK[cur ^ 1][0] : (char*)&sV[cur ^ 1][0];
      async16(gp0, base + ldsOff[0]);
      async16(gp1, base + ldsOff[1]);
      async16(gp2, base + ldsOff[2]);
      async16(gp3, base + ldsOff[3]);
      gp0 += gstride; gp1 += gstride; gp2 += gstride; gp3 += gstride;
    }
    const unsigned short* sKc = sK[cur];
    const unsigned short* sVc = sV[cur];

    // S^T(log2) = K Q^T, kf shared across stripes: lane q=lane15, k=n*16+lhi*4+r
    f32x4 sacc[2][4];
#pragma unroll
    for (int s = 0; s < 2; s++)
#pragma unroll
      for (int n = 0; n < 4; n++) sacc[s][n] = zero;
    __builtin_amdgcn_s_setprio(1);
#pragma unroll
    for (int n = 0; n < 4; n++) {
      int row = n * 16 + lane15;
#pragma unroll
      for (int kc = 0; kc < 4; kc++) {
        bf16x8 kf = *(const bf16x8*)((const char*)sKc + row * 256 +
                                     ((kc * 64 + lhi * 16) ^ ((row & 7) << 4)));
        sacc[0][n] = __builtin_amdgcn_mfma_f32_16x16x32_bf16(kf, qf[0][kc], sacc[0][n], 0, 0, 0);
        sacc[1][n] = __builtin_amdgcn_mfma_f32_16x16x32_bf16(kf, qf[1][kc], sacc[1][n], 0, 0, 0);
      }
    }
    __builtin_amdgcn_s_setprio(0);

    // per-stripe max (log2 units)
    float pmax[2];
#pragma unroll
    for (int s = 0; s < 2; s++) {
      float a0 = fmaxf(fmaxf(sacc[s][0][0], sacc[s][0][1]), fmaxf(sacc[s][0][2], sacc[s][0][3]));
      float a1 = fmaxf(fmaxf(sacc[s][1][0], sacc[s][1][1]), fmaxf(sacc[s][1][2], sacc[s][1][3]));
      float a2 = fmaxf(fmaxf(sacc[s][2][0], sacc[s][2][1]), fmaxf(sacc[s][2][2], sacc[s][2][3]));
      float a3 = fmaxf(fmaxf(sacc[s][3][0], sacc[s][3][1]), fmaxf(sacc[s][3][2], sacc[s][3][3]));
      float pm = fmaxf(fmaxf(a0, a1), fmaxf(a2, a3));
      pm = fmaxf(pm, __shfl_xor(pm, 16));
      pm = fmaxf(pm, __shfl_xor(pm, 32));
      pmax[s] = pm;
    }
    // single merged defer-max branch (rescale both stripes when any exceeds)
    if (!__all(fmaxf(pmax[0] - mrun[0], pmax[1] - mrun[1]) <= THR)) {
#pragma unroll
      for (int s = 0; s < 2; s++) {
        float mnew = fmaxf(mrun[s], pmax[s]);
        float alpha = exp2f(mrun[s] - mnew);
        lrun[s] *= alpha;
        float af[4];
#pragma unroll
        for (int r = 0; r < 4; r++) af[r] = __shfl(alpha, lhi * 4 + r);
#pragma unroll
        for (int nf = 0; nf < 8; nf++)
#pragma unroll
          for (int r = 0; r < 4; r++) oacc[s][nf][r] *= af[r];
        mrun[s] = mnew;
      }
    }
    // branch-free: exp2 + sum + pack, both stripes
#pragma unroll
    for (int s = 0; s < 2; s++) {
      float rs = 0.f;
      float p[4][4];
#pragma unroll
      for (int n = 0; n < 4; n++)
#pragma unroll
        for (int r = 0; r < 4; r++) {
          float pv = exp2f(sacc[s][n][r] - mrun[s]);
          p[n][r] = pv;
          rs += pv;
        }
      rs += __shfl_xor(rs, 16);
      rs += __shfl_xor(rs, 32);
      lrun[s] += rs;
#pragma unroll
      for (int n = 0; n < 4; n++) {
        uint2 st;
        st.x = cvt_pk_bf16(p[n][0], p[n][1]);
        st.y = cvt_pk_bf16(p[n][2], p[n][3]);
        *(uint2*)&sP[w][(s * 16 + lane15) * 72 + n * 16 + lhi * 4] = st;
      }
    }
    // wave-local cross-lane write->read fence (rule 18)
    asm volatile("s_waitcnt lgkmcnt(0)" ::: "memory");
    __builtin_amdgcn_sched_barrier(0);
    bf16x8 pf[2][2];
#pragma unroll
    for (int s = 0; s < 2; s++)
#pragma unroll
      for (int kc = 0; kc < 2; kc++)
        pf[s][kc] = *(const bf16x8*)&sP[w][(s * 16 + lane15) * 72 + kc * 32 + lhi * 8];

    // O += P * V, vf shared across stripes
    __builtin_amdgcn_s_setprio(1);
#pragma unroll
    for (int nf = 0; nf < 8; nf++) {
      int row = nf * 16 + lane15;
#pragma unroll
      for (int kc = 0; kc < 2; kc++) {
        bf16x8 vf = *(const bf16x8*)((const char*)sVc + row * 128 +
                                     ((kc * 64 + lhi * 16) ^ ((row & 7) << 4)));
        oacc[0][nf] = __builtin_amdgcn_mfma_f32_16x16x32_bf16(pf[0][kc], vf, oacc[0][nf], 0, 0, 0);
        oacc[1][nf] = __builtin_amdgcn_mfma_f32_16x16x32_bf16(pf[1][kc], vf, oacc[1][nf], 0, 0, 0);
      }
    }
    __builtin_amdgcn_s_setprio(0);
  }

  // epilogue: oacc[s] rows q=lhi*4+r, cols d=nf*16+lane15
#pragma unroll
  for (int s = 0; s < 2; s++) {
    float inv = 1.0f / lrun[s];
    float invr[4];
#pragma unroll
    for (int r = 0; r < 4; r++) invr[r] = __shfl(inv, lhi * 4 + r);
    unsigned short* Og = ctx + ((size_t)(b * S_ + q0 + w * 32 + s * 16)) * D_ + h * HD_;
#pragma unroll
    for (int r = 0; r < 4; r++) {
      int qrow = lhi * 4 + r;
#pragma unroll
      for (int nf = 0; nf < 8; nf++)
        Og[(size_t)qrow * D_ + nf * 16 + lane15] = f_to_bf(oacc[s][nf][r] * invr[r]);
    }
  }
}

// ---------------- launcher ----------------
extern "C" void kernel_launch(void* const* d_in, const int* in_sizes, int n_in,
                              void* d_out, int out_size, void* d_ws, size_t ws_size,
                              hipStream_t stream) {
  (void)in_sizes; (void)n_in; (void)out_size; (void)ws_size;
  const float* x = (const float*)d_in[0];
  const float* wq = (const float*)d_in[1];
  const float* wk = (const float*)d_in[2];
  const float* wv = (const float*)d_in[3];
  const float* wo = (const float*)d_in[4];
  float* out = (float*)d_out;

  char* ws = (char*)d_ws;
  const size_t MB = 1024 * 1024;
  unsigned short* xb  = (unsigned short*)(ws + 0 * MB);    // 16 MB; later aliased as ctx
  unsigned short* wqb = (unsigned short*)(ws + 16 * MB);   // 8 MB (wq..wo contiguous)
  unsigned short* wkb = (unsigned short*)(ws + 24 * MB);
  unsigned short* wvb = (unsigned short*)(ws + 32 * MB);
  unsigned short* wob = (unsigned short*)(ws + 40 * MB);
  unsigned short* Qb  = (unsigned short*)(ws + 48 * MB);   // 16 MB
  unsigned short* Kb  = (unsigned short*)(ws + 64 * MB);   // 16 MB
  unsigned short* Vtb = (unsigned short*)(ws + 80 * MB);   // 16 MB
  float* cosT = (float*)(ws + 96 * MB);                    // 0.5 MB
  float* sinT = (float*)(ws + 96 * MB + 524288);           // 0.5 MB
  unsigned short* ctxb = xb;  // x_bf16 dead after QKV GEMMs

  const int M = B_ * S_;  // 4096

  conv_all<<<24576, 256, 0, stream>>>(x, wq, wk, wv, wo, xb, wqb);
  rope_table_kernel<<<512, 256, 0, stream>>>(cosT, sinT);

  dim3 ggrid(M / 128, D_ / 128);
  gemm_bt<0><<<ggrid, 256, 0, stream>>>(xb, wqb, Qb, nullptr, nullptr, nullptr, M, D_, D_);
  gemm_bt<2><<<ggrid, 256, 0, stream>>>(xb, wkb, Kb, nullptr, cosT, sinT, M, D_, D_);
  gemm_bt<3><<<ggrid, 256, 0, stream>>>(xb, wvb, Vtb, nullptr, nullptr, nullptr, M, D_, D_);

  attn_kernel<<<dim3(8, 32), 512, 0, stream>>>(Qb, Kb, Vtb, ctxb, cosT, sinT);

  gemm_bt<1><<<ggrid, 256, 0, stream>>>(ctxb, wob, nullptr, out, nullptr, nullptr, M, D_, D_);
}